// Round 9
// baseline (276.863 us; speedup 1.0000x reference)
//
#include <hip/hip_runtime.h>
#include <hip/hip_cooperative_groups.h>
#include <math.h>

namespace cg = cooperative_groups;

#define PCAP 512  // per-tile-pair LDS positive staging (mean ~256, sd ~21)

typedef float f32x4 __attribute__((ext_vector_type(4)));

// ---------------------------------------------------------------------------
// One cooperative kernel, three phases:
//   0: normalize rows -> fp8 e4m3, zero unsim/accum/pcur      (grid.sync)
//   1: persistent loop over upper-tri 128x128 tile pairs:
//      fp8 MFMA sim + exp + label-mask row/col sums -> unsim,
//      positive (idx,s) records -> LDS stage -> posBuf         (grid.sync)
//   2: stream records: log(exp(s)+unsim[idx]) - s, reduce      (grid.sync)
//      block 0 writes loss_sum / n_pos.
// Grid size is runtime-determined (occupancy query) — all loops grid-stride.
__global__ __launch_bounds__(256, 3) void fused_kernel(
    const float* __restrict__ X, const int* __restrict__ lab,
    unsigned char* __restrict__ Y8, float* __restrict__ unsim,
    float* __restrict__ accum, uint2* __restrict__ posBuf,
    int* __restrict__ pcur, int nt, int nblk, float inv_sqrtT,
    float* __restrict__ out) {
  __shared__ unsigned char As[128][128];  // chunk c at (c ^ (row&7)) * 16
  __shared__ unsigned char Bs[128][128];
  __shared__ int labR[128], labC[128];
  __shared__ float rsumS[128], csumS[128];
  __shared__ uint2 posS[PCAP];
  __shared__ int posCnt, gbaseS;

  cg::grid_group grid = cg::this_grid();
  const int t = threadIdx.x;
  const int N = nt * 128;

  // ---- phase 0: normalize rows (8 per block-iter, 32 lanes per row) ----
  for (int r0 = blockIdx.x * 8; r0 < N; r0 += gridDim.x * 8) {
    int row = r0 + (t >> 5);
    int l32 = t & 31;
    float4 v = ((const float4*)(X + (size_t)row * 128))[l32];
    float s = v.x * v.x + v.y * v.y + v.z * v.z + v.w * v.w;
    s += __shfl_xor(s, 1);
    s += __shfl_xor(s, 2);
    s += __shfl_xor(s, 4);
    s += __shfl_xor(s, 8);
    s += __shfl_xor(s, 16);
    float inv = inv_sqrtT * rsqrtf(fmaxf(s, 1e-24f));
    int pk = __builtin_amdgcn_cvt_pk_fp8_f32(v.x * inv, v.y * inv, 0, false);
    pk = __builtin_amdgcn_cvt_pk_fp8_f32(v.z * inv, v.w * inv, pk, true);
    ((unsigned int*)(Y8 + (size_t)row * 128))[l32] = (unsigned)pk;
    if (l32 == 0) unsim[row] = 0.f;
  }
  if (blockIdx.x == 0 && t < 8) accum[t] = 0.f;  // accum[0..5], pcur(6,7)
  grid.sync();

  // ---- phase 1: persistent tile loop ----
  const int w = t >> 6, lane = t & 63;
  const int quad = lane >> 4, l16 = lane & 15;
  const int rbase = (w >> 1) * 64, cbase = (w & 1) * 64;
  const int sw = l16 & 7;
  const float4* Yg = (const float4*)Y8;  // row = 8 float4 chunks (128 B)

  for (int b = blockIdx.x; b < nblk; b += gridDim.x) {
    __syncthreads();  // protect As/Bs/posS reuse across iterations
    if (t == 0) posCnt = 0;

    // decode linear block id -> (bi, bj), bi <= bj (triangular)
    float ntf = (float)nt;
    int bi = (int)((2.f * ntf + 1.f -
                    sqrtf((2.f * ntf + 1.f) * (2.f * ntf + 1.f) -
                          8.f * (float)b)) *
                   0.5f);
    if (bi < 0) bi = 0;
    while ((bi + 1) * nt - ((bi + 1) * bi) / 2 <= b) ++bi;
    while (bi * nt - (bi * (bi - 1)) / 2 > b) --bi;
    int bj = bi + (b - (bi * nt - (bi * (bi - 1)) / 2));
    const int i0 = bi * 128, j0 = bj * 128;
    const bool offdiag = (bi != bj);

#pragma unroll
    for (int c = t; c < 1024; c += 256) {
      int row = c >> 3, kc = c & 7;
      int swc = (kc ^ (row & 7)) << 4;
      *(float4*)&As[row][swc] = Yg[(size_t)(i0 + row) * 8 + kc];
      *(float4*)&Bs[row][swc] = Yg[(size_t)(j0 + row) * 8 + kc];
    }
    if (t < 128) {
      labR[t] = lab[i0 + t];
      labC[t] = lab[j0 + t];
      rsumS[t] = 0.f;
      csumS[t] = 0.f;
    }
    __syncthreads();

    f32x4 acc[4][4] = {};
#pragma unroll
    for (int ks = 0; ks < 4; ++ks) {
      const int ch = ks * 2 + (quad >> 1);
      const int off = ((ch ^ sw) << 4) + ((quad & 1) << 3);
      long af[4], bf[4];
#pragma unroll
      for (int p = 0; p < 4; ++p)
        af[p] = *(const long*)&As[rbase + p * 16 + l16][off];
#pragma unroll
      for (int p = 0; p < 4; ++p)
        bf[p] = *(const long*)&Bs[cbase + p * 16 + l16][off];
#pragma unroll
      for (int pi = 0; pi < 4; ++pi)
#pragma unroll
        for (int pj = 0; pj < 4; ++pj)
          acc[pi][pj] = __builtin_amdgcn_mfma_f32_16x16x32_fp8_fp8(
              af[pi], bf[pj], acc[pi][pj], 0, 0, 0);
    }

    // epilogue: masked exp row/col partials + rare positive append
    int lr[4][4], lc[4];
#pragma unroll
    for (int pi = 0; pi < 4; ++pi)
#pragma unroll
      for (int r = 0; r < 4; ++r)
        lr[pi][r] = labR[rbase + pi * 16 + quad * 4 + r];
#pragma unroll
    for (int pj = 0; pj < 4; ++pj) lc[pj] = labC[cbase + pj * 16 + l16];

    float rowp[4][4] = {};
    float colp[4] = {0.f, 0.f, 0.f, 0.f};
#pragma unroll
    for (int pi = 0; pi < 4; ++pi)
#pragma unroll
      for (int pj = 0; pj < 4; ++pj)
#pragma unroll
        for (int r = 0; r < 4; ++r) {
          const bool same = (lr[pi][r] == lc[pj]);
          float s = acc[pi][pj][r];
          float e = same ? 0.f : __expf(s);
          rowp[pi][r] += e;
          colp[pj] += e;
          if (same) {  // ~1/128 dense
            const int gi = i0 + rbase + pi * 16 + quad * 4 + r;
            const int gj = j0 + cbase + pj * 16 + l16;
            if (offdiag || (gi != gj)) {
              int nadd = offdiag ? 2 : 1;
              int s0 = atomicAdd(&posCnt, nadd);
              unsigned sb = __float_as_uint(s);
              uint2 e0 = {(unsigned)gi, sb};
              if (s0 < PCAP) posS[s0] = e0;
              else posBuf[atomicAdd(pcur, 1)] = e0;
              if (offdiag) {
                uint2 e1 = {(unsigned)gj, sb};
                if (s0 + 1 < PCAP) posS[s0 + 1] = e1;
                else posBuf[atomicAdd(pcur, 1)] = e1;
              }
            }
          }
        }

    // row sums -> LDS stage
#pragma unroll
    for (int pi = 0; pi < 4; ++pi)
#pragma unroll
      for (int r = 0; r < 4; ++r) {
        float v = rowp[pi][r];
        v += __shfl_xor(v, 1);
        v += __shfl_xor(v, 2);
        v += __shfl_xor(v, 4);
        v += __shfl_xor(v, 8);
        if (l16 == 0) atomicAdd(&rsumS[rbase + pi * 16 + quad * 4 + r], v);
      }
    // col sums -> LDS stage
#pragma unroll
    for (int pj = 0; pj < 4; ++pj) {
      float v = colp[pj];
      v += __shfl_xor(v, 16);
      v += __shfl_xor(v, 32);
      if (quad == 0) atomicAdd(&csumS[cbase + pj * 16 + l16], v);
    }
    __syncthreads();

    // flush: ONE global atomic per row/col; one pcur atomic per tile pair
    if (t < 128) {
      atomicAdd(&unsim[i0 + t], rsumS[t]);
    } else if (offdiag) {
      atomicAdd(&unsim[j0 + (t - 128)], csumS[t - 128]);
    }
    int total = posCnt < PCAP ? posCnt : PCAP;
    if (t == 0) gbaseS = atomicAdd(pcur, total);
    __syncthreads();
    for (int e = t; e < total; e += 256) posBuf[gbaseS + e] = posS[e];
  }
  grid.sync();

  // ---- phase 2: stream positive records ----
  {
    int n = *pcur;
    float local = 0.f;
    for (int p = blockIdx.x * 256 + t; p < n; p += gridDim.x * 256) {
      uint2 e = posBuf[p];
      float s = __uint_as_float(e.y);
      local += __logf(__expf(s) + unsim[e.x]) - s;
    }
#pragma unroll
    for (int m = 1; m < 64; m <<= 1) local += __shfl_xor(local, m);
    if (lane == 0) rsumS[w] = local;  // reuse LDS
    __syncthreads();
    if (t == 0)
      atomicAdd(&accum[0], rsumS[0] + rsumS[1] + rsumS[2] + rsumS[3]);
    __threadfence();
    grid.sync();
    if (blockIdx.x == 0 && t == 0) out[0] = accum[0] / (float)n;
  }
}

// ---------------------------------------------------------------------------
extern "C" void kernel_launch(void* const* d_in, const int* in_sizes, int n_in,
                              void* d_out, int out_size, void* d_ws,
                              size_t ws_size, hipStream_t stream) {
  const float* X = (const float*)d_in[0];
  const int* lab = (const int*)d_in[1];
  float* out = (float*)d_out;

  const int N = in_sizes[1];  // 8192; D fixed at 128

  // workspace layout
  unsigned char* Y8 = (unsigned char*)d_ws;       // N*128 fp8 (1 MB)
  float* unsim = (float*)(Y8 + (size_t)N * 128);  // N f32
  float* accum = unsim + N;                       // [0] loss; pcur at +6
  int* pcur = (int*)(accum + 6);                  // record cursor (+ pad)
  uint2* posBuf = (uint2*)(pcur + 2);             // ~524k entries (4.2 MB)

  float inv_sqrtT = 2.2360679775f;  // 1/sqrt(0.2)
  int nt = N / 128;                 // 64 tiles per dim
  int nblk = nt * (nt + 1) / 2;     // 2080 upper-tri tile pairs

  // Runtime co-residency query (host-side, graph-capture safe): R8 failed
  // because a 4-blocks/CU guess exceeded the schedulable LDS (~128 KB/CU
  // effective; measured occupancy in R5/R7 was ~3 blocks/CU at 39 KB).
  static int coopGrid = 0;  // computed once; same kernel every call
  if (coopGrid == 0) {
    int perCU = 0;
    if (hipOccupancyMaxActiveBlocksPerMultiprocessor(
            &perCU, (const void*)fused_kernel, 256, 0) != hipSuccess ||
        perCU < 1)
      perCU = 1;
    int cus = 256;
    hipDeviceProp_t prop;
    if (hipGetDeviceProperties(&prop, 0) == hipSuccess &&
        prop.multiProcessorCount > 0)
      cus = prop.multiProcessorCount;
    coopGrid = perCU * cus;
    if (coopGrid > 1024) coopGrid = 1024;
    if (coopGrid < 256) coopGrid = 256;
  }

  void* args[] = {(void*)&X,     (void*)&lab,   (void*)&Y8,
                  (void*)&unsim, (void*)&accum, (void*)&posBuf,
                  (void*)&pcur,  (void*)&nt,    (void*)&nblk,
                  (void*)&inv_sqrtT, (void*)&out};
  hipLaunchCooperativeKernel((void*)fused_kernel, dim3(coopGrid), dim3(256),
                             args, 0, stream);
}

// Round 10
// 165.102 us; speedup vs baseline: 1.6769x; 1.6769x over previous
//
#include <hip/hip_runtime.h>
#include <math.h>

#define PCAP 512  // per-block LDS positive-pair staging capacity

typedef float f32x4 __attribute__((ext_vector_type(4)));

// ---------------------------------------------------------------------------
// Kernel 1: fp8 MFMA similarity pass over upper-triangular 128x128 tile
// pairs (R7 structure), with row normalization FUSED into staging: each
// block loads its two X bands (fp32, L2-resident after first touch),
// computes row norms with half-wave shuffles, converts to fp8 e4m3 and
// writes the XOR-swizzled LDS tiles directly. No norm kernel, no Y8 buffer.
// Positives: LDS-staged append, ONE global pcur atomic per block.
// unsim row/col sums: LDS-staged, one global atomic per row per block.
__global__ __launch_bounds__(256, 4) void pass1_kernel(
    const float* __restrict__ X, const int* __restrict__ lab,
    float* __restrict__ unsim, uint2* __restrict__ posBuf,
    int* __restrict__ pcur, int nt, float inv_sqrtT) {
  __shared__ unsigned char As[128][128];  // chunk c at (c ^ (row&7)) * 16
  __shared__ unsigned char Bs[128][128];
  __shared__ int labR[128], labC[128];
  __shared__ float rsumS[128], csumS[128];
  __shared__ uint2 posS[PCAP];
  __shared__ int posCnt, gbaseS;

  // decode linear block id -> (bi, bj), bi <= bj (triangular)
  int b = blockIdx.x;
  float ntf = (float)nt;
  int bi = (int)((2.f * ntf + 1.f -
                  sqrtf((2.f * ntf + 1.f) * (2.f * ntf + 1.f) - 8.f * (float)b)) *
                 0.5f);
  if (bi < 0) bi = 0;
  while ((bi + 1) * nt - ((bi + 1) * bi) / 2 <= b) ++bi;
  while (bi * nt - (bi * (bi - 1)) / 2 > b) --bi;
  int bj = bi + (b - (bi * nt - (bi * (bi - 1)) / 2));
  const int i0 = bi * 128, j0 = bj * 128;
  const bool offdiag = (bi != bj);

  const int t = threadIdx.x;
  const int w = t >> 6, lane = t & 63;

  // ---- staging with fused normalization ----
  // Wave w handles rows r = w, w+4, ... of BOTH bands: lanes 0-31 do
  // A-row (i0+r), lanes 32-63 do B-row (j0+r). 32 lanes per row, float4
  // each; half-wave shfl reduction stays within the 32-lane half.
  {
    const int half = lane >> 5, l32 = lane & 31;
    const int base = half ? j0 : i0;
    unsigned char* dst = half ? &Bs[0][0] : &As[0][0];
    for (int r = w; r < 128; r += 4) {
      float4 v = ((const float4*)(X + (size_t)(base + r) * 128))[l32];
      float s = v.x * v.x + v.y * v.y + v.z * v.z + v.w * v.w;
      s += __shfl_xor(s, 1);
      s += __shfl_xor(s, 2);
      s += __shfl_xor(s, 4);
      s += __shfl_xor(s, 8);
      s += __shfl_xor(s, 16);
      float inv = inv_sqrtT * rsqrtf(fmaxf(s, 1e-24f));
      int pk = __builtin_amdgcn_cvt_pk_fp8_f32(v.x * inv, v.y * inv, 0, false);
      pk = __builtin_amdgcn_cvt_pk_fp8_f32(v.z * inv, v.w * inv, pk, true);
      const int chunk = l32 >> 2;
      const int swc = ((chunk ^ (r & 7)) << 4) + ((l32 & 3) << 2);
      *(unsigned int*)(dst + r * 128 + swc) = (unsigned)pk;
    }
  }
  if (t < 128) {
    labR[t] = lab[i0 + t];
    labC[t] = lab[j0 + t];
    rsumS[t] = 0.f;
    csumS[t] = 0.f;
  }
  if (t == 0) posCnt = 0;
  __syncthreads();

  const int quad = lane >> 4, l16 = lane & 15;
  const int rbase = (w >> 1) * 64, cbase = (w & 1) * 64;
  const int sw = l16 & 7;

  f32x4 acc[4][4] = {};
#pragma unroll
  for (int ks = 0; ks < 4; ++ks) {
    const int ch = ks * 2 + (quad >> 1);
    const int off = ((ch ^ sw) << 4) + ((quad & 1) << 3);
    long af[4], bf[4];
#pragma unroll
    for (int p = 0; p < 4; ++p)
      af[p] = *(const long*)&As[rbase + p * 16 + l16][off];
#pragma unroll
    for (int p = 0; p < 4; ++p)
      bf[p] = *(const long*)&Bs[cbase + p * 16 + l16][off];
#pragma unroll
    for (int pi = 0; pi < 4; ++pi)
#pragma unroll
      for (int pj = 0; pj < 4; ++pj)
        acc[pi][pj] = __builtin_amdgcn_mfma_f32_16x16x32_fp8_fp8(
            af[pi], bf[pj], acc[pi][pj], 0, 0, 0);
  }

  // ---- epilogue ----
  int lr[4][4], lc[4];
#pragma unroll
  for (int pi = 0; pi < 4; ++pi)
#pragma unroll
    for (int r = 0; r < 4; ++r) lr[pi][r] = labR[rbase + pi * 16 + quad * 4 + r];
#pragma unroll
  for (int pj = 0; pj < 4; ++pj) lc[pj] = labC[cbase + pj * 16 + l16];

  float rowp[4][4] = {};
  float colp[4] = {0.f, 0.f, 0.f, 0.f};
#pragma unroll
  for (int pi = 0; pi < 4; ++pi)
#pragma unroll
    for (int pj = 0; pj < 4; ++pj)
#pragma unroll
      for (int r = 0; r < 4; ++r) {
        const bool same = (lr[pi][r] == lc[pj]);
        float s = acc[pi][pj][r];
        float e = same ? 0.f : __expf(s);
        rowp[pi][r] += e;
        colp[pj] += e;
        if (same) {  // rare (~1/128): LDS-staged append
          const int gi = i0 + rbase + pi * 16 + quad * 4 + r;
          const int gj = j0 + cbase + pj * 16 + l16;
          if (offdiag || (gi != gj)) {
            int nadd = offdiag ? 2 : 1;
            int s0 = atomicAdd(&posCnt, nadd);
            unsigned sb = __float_as_uint(s);
            uint2 e0 = {(unsigned)gi, sb};
            if (s0 < PCAP) posS[s0] = e0;
            else posBuf[atomicAdd(pcur, 1)] = e0;
            if (offdiag) {
              uint2 e1 = {(unsigned)gj, sb};
              if (s0 + 1 < PCAP) posS[s0 + 1] = e1;
              else posBuf[atomicAdd(pcur, 1)] = e1;
            }
          }
        }
      }

  // row sums: 4-shfl reduce over the 16 cols, stage in LDS
#pragma unroll
  for (int pi = 0; pi < 4; ++pi)
#pragma unroll
    for (int r = 0; r < 4; ++r) {
      float v = rowp[pi][r];
      v += __shfl_xor(v, 1);
      v += __shfl_xor(v, 2);
      v += __shfl_xor(v, 4);
      v += __shfl_xor(v, 8);
      if (l16 == 0) atomicAdd(&rsumS[rbase + pi * 16 + quad * 4 + r], v);
    }
  // col sums (mirror band): reduce across quads, stage in LDS
#pragma unroll
  for (int pj = 0; pj < 4; ++pj) {
    float v = colp[pj];
    v += __shfl_xor(v, 16);
    v += __shfl_xor(v, 32);
    if (quad == 0) atomicAdd(&csumS[cbase + pj * 16 + l16], v);
  }
  __syncthreads();

  // flush: ONE global atomic per row (and per col if off-diagonal)
  if (t < 128) {
    atomicAdd(&unsim[i0 + t], rsumS[t]);
  } else if (offdiag) {
    atomicAdd(&unsim[j0 + (t - 128)], csumS[t - 128]);
  }
  // flush positive records: one global cursor atomic per block
  int total = posCnt < PCAP ? posCnt : PCAP;
  if (t == 0) gbaseS = atomicAdd(pcur, total);
  __syncthreads();
  for (int e = t; e < total; e += 256) posBuf[gbaseS + e] = posS[e];
}

// ---------------------------------------------------------------------------
// Kernel 2: stream positive records: term = log(exp(s) + unsim[idx]) - s,
// finalize fused via last-block-done pattern.
__global__ __launch_bounds__(256) void pass3_kernel(
    const uint2* __restrict__ posBuf, int* __restrict__ pcur,
    const float* __restrict__ unsim, float* __restrict__ accum,
    float* __restrict__ out) {
  int n = *pcur;
  float local = 0.f;
  int stride = 256 * gridDim.x;
  for (int p = blockIdx.x * 256 + threadIdx.x; p < n; p += stride) {
    uint2 e = posBuf[p];
    float s = __uint_as_float(e.y);
    local += __logf(__expf(s) + unsim[e.x]) - s;
  }
  __shared__ float red[4];
#pragma unroll
  for (int msk = 1; msk < 64; msk <<= 1) local += __shfl_xor(local, msk);
  int lane = threadIdx.x & 63, w = threadIdx.x >> 6;
  if (lane == 0) red[w] = local;
  __syncthreads();
  if (threadIdx.x == 0) {
    atomicAdd(&accum[0], red[0] + red[1] + red[2] + red[3]);
    __threadfence();
    int* done = (int*)&accum[2];
    if (atomicAdd(done, 1) == (int)gridDim.x - 1) {
      float ls = __hip_atomic_load(&accum[0], __ATOMIC_ACQUIRE,
                                   __HIP_MEMORY_SCOPE_AGENT);
      out[0] = ls / (float)n;
    }
  }
}

// ---------------------------------------------------------------------------
extern "C" void kernel_launch(void* const* d_in, const int* in_sizes, int n_in,
                              void* d_out, int out_size, void* d_ws,
                              size_t ws_size, hipStream_t stream) {
  const float* X = (const float*)d_in[0];
  const int* lab = (const int*)d_in[1];
  float* out = (float*)d_out;

  const int N = in_sizes[1];  // 8192; D fixed at 128

  // workspace layout
  float* unsim = (float*)d_ws;           // N f32
  float* accum = unsim + N;              // [0] loss, [2] done ctr
  int* pcur = (int*)(accum + 6);         // record cursor (+ pad)
  uint2* posBuf = (uint2*)(pcur + 2);    // ~524k entries (4.2 MB)

  // zero unsim + accum + pcur (one contiguous 33 KB memset)
  hipMemsetAsync(unsim, 0, (size_t)(N + 8) * sizeof(float), stream);

  const float inv_sqrtT = 2.2360679775f;  // 1/sqrt(0.2)
  const int nt = N / 128;                 // 64 tiles per dim
  const int nblk = nt * (nt + 1) / 2;     // 2080 upper-tri tile pairs
  pass1_kernel<<<nblk, 256, 0, stream>>>(X, lab, unsim, posBuf, pcur, nt,
                                         inv_sqrtT);
  pass3_kernel<<<512, 256, 0, stream>>>(posBuf, pcur, unsim, accum, out);
}

// Round 11
// 145.276 us; speedup vs baseline: 1.9058x; 1.1365x over previous
//
#include <hip/hip_runtime.h>
#include <math.h>

#define PCAP 512  // per-block LDS positive-pair staging capacity

typedef float f32x4 __attribute__((ext_vector_type(4)));

// ---------------------------------------------------------------------------
// Kernel 1: row normalization (4 rows per block, one per wave) + zero
// accum/pcur. Output: fp8 e4m3 (OCP) rows for the MFMA pass.
__global__ __launch_bounds__(256) void norm_kernel(
    const float* __restrict__ X, unsigned char* __restrict__ Y8,
    float* __restrict__ accum, float inv_sqrtT) {
  int t = threadIdx.x;
  int w = t >> 6, lane = t & 63;
  int row = blockIdx.x * 4 + w;
  float2 v = ((const float2*)(X + (size_t)row * 128))[lane];
  float s = v.x * v.x + v.y * v.y;
#pragma unroll
  for (int m = 1; m < 64; m <<= 1) s += __shfl_xor(s, m);
  float inv = inv_sqrtT * rsqrtf(fmaxf(s, 1e-24f));
  int packed = __builtin_amdgcn_cvt_pk_fp8_f32(v.x * inv, v.y * inv, 0, false);
  ((unsigned short*)(Y8 + (size_t)row * 128))[lane] =
      (unsigned short)(packed & 0xffff);
  if (blockIdx.x == 0 && t < 8) accum[t] = 0.f;  // accum[0..5] + pcur(6,7)
}

// ---------------------------------------------------------------------------
// Kernel 2: fp8 MFMA similarity pass over upper-triangular 128x128 tile
// pairs (R7 structure). Row/col exp-sums now go to PER-BLOCK partial arrays
// with plain coalesced stores — the R7 global atomicAdds into unsim[8192]
// funneled ~400k RMWs into ~1k cache lines and gated block retirement
// (24 us/block vs 1.7 us issue). Positives: LDS-staged append, ONE global
// pcur atomic per block.
__global__ __launch_bounds__(256, 4) void pass1_kernel(
    const unsigned char* __restrict__ Y8, const int* __restrict__ lab,
    float* __restrict__ rpart, float* __restrict__ cpart,
    uint2* __restrict__ posBuf, int* __restrict__ pcur, int nt) {
  __shared__ unsigned char As[128][128];  // chunk c at (c ^ (row&7)) * 16
  __shared__ unsigned char Bs[128][128];
  __shared__ int labR[128], labC[128];
  __shared__ float rsumS[128], csumS[128];
  __shared__ uint2 posS[PCAP];
  __shared__ int posCnt, gbaseS;

  // decode linear block id -> (bi, bj), bi <= bj (triangular)
  int b = blockIdx.x;
  float ntf = (float)nt;
  int bi = (int)((2.f * ntf + 1.f -
                  sqrtf((2.f * ntf + 1.f) * (2.f * ntf + 1.f) - 8.f * (float)b)) *
                 0.5f);
  if (bi < 0) bi = 0;
  while ((bi + 1) * nt - ((bi + 1) * bi) / 2 <= b) ++bi;
  while (bi * nt - (bi * (bi - 1)) / 2 > b) --bi;
  int bj = bi + (b - (bi * nt - (bi * (bi - 1)) / 2));
  const int i0 = bi * 128, j0 = bj * 128;
  const bool offdiag = (bi != bj);

  const int t = threadIdx.x;
  const float4* Yg = (const float4*)Y8;  // row = 8 float4 chunks (128 B)
#pragma unroll
  for (int c = t; c < 1024; c += 256) {
    int row = c >> 3, kc = c & 7;
    int swc = (kc ^ (row & 7)) << 4;
    *(float4*)&As[row][swc] = Yg[(size_t)(i0 + row) * 8 + kc];
    *(float4*)&Bs[row][swc] = Yg[(size_t)(j0 + row) * 8 + kc];
  }
  if (t < 128) {
    labR[t] = lab[i0 + t];
    labC[t] = lab[j0 + t];
    rsumS[t] = 0.f;
    csumS[t] = 0.f;
  }
  if (t == 0) posCnt = 0;
  __syncthreads();

  const int w = t >> 6, lane = t & 63;
  const int quad = lane >> 4, l16 = lane & 15;
  const int rbase = (w >> 1) * 64, cbase = (w & 1) * 64;
  const int sw = l16 & 7;

  f32x4 acc[4][4] = {};
#pragma unroll
  for (int ks = 0; ks < 4; ++ks) {
    const int ch = ks * 2 + (quad >> 1);
    const int off = ((ch ^ sw) << 4) + ((quad & 1) << 3);
    long af[4], bf[4];
#pragma unroll
    for (int p = 0; p < 4; ++p)
      af[p] = *(const long*)&As[rbase + p * 16 + l16][off];
#pragma unroll
    for (int p = 0; p < 4; ++p)
      bf[p] = *(const long*)&Bs[cbase + p * 16 + l16][off];
#pragma unroll
    for (int pi = 0; pi < 4; ++pi)
#pragma unroll
      for (int pj = 0; pj < 4; ++pj)
        acc[pi][pj] = __builtin_amdgcn_mfma_f32_16x16x32_fp8_fp8(
            af[pi], bf[pj], acc[pi][pj], 0, 0, 0);
  }

  // ---- epilogue ----
  int lr[4][4], lc[4];
#pragma unroll
  for (int pi = 0; pi < 4; ++pi)
#pragma unroll
    for (int r = 0; r < 4; ++r) lr[pi][r] = labR[rbase + pi * 16 + quad * 4 + r];
#pragma unroll
  for (int pj = 0; pj < 4; ++pj) lc[pj] = labC[cbase + pj * 16 + l16];

  float rowp[4][4] = {};
  float colp[4] = {0.f, 0.f, 0.f, 0.f};
#pragma unroll
  for (int pi = 0; pi < 4; ++pi)
#pragma unroll
    for (int pj = 0; pj < 4; ++pj)
#pragma unroll
      for (int r = 0; r < 4; ++r) {
        const bool same = (lr[pi][r] == lc[pj]);
        float s = acc[pi][pj][r];
        float e = same ? 0.f : __expf(s);
        rowp[pi][r] += e;
        colp[pj] += e;
        if (same) {  // rare (~1/128): LDS-staged append
          const int gi = i0 + rbase + pi * 16 + quad * 4 + r;
          const int gj = j0 + cbase + pj * 16 + l16;
          if (offdiag || (gi != gj)) {
            int nadd = offdiag ? 2 : 1;
            int s0 = atomicAdd(&posCnt, nadd);
            unsigned sb = __float_as_uint(s);
            uint2 e0 = {(unsigned)gi, sb};
            if (s0 < PCAP) posS[s0] = e0;
            else posBuf[atomicAdd(pcur, 1)] = e0;
            if (offdiag) {
              uint2 e1 = {(unsigned)gj, sb};
              if (s0 + 1 < PCAP) posS[s0 + 1] = e1;
              else posBuf[atomicAdd(pcur, 1)] = e1;
            }
          }
        }
      }

  // row sums: 4-shfl reduce over the 16 cols, stage in LDS
#pragma unroll
  for (int pi = 0; pi < 4; ++pi)
#pragma unroll
    for (int r = 0; r < 4; ++r) {
      float v = rowp[pi][r];
      v += __shfl_xor(v, 1);
      v += __shfl_xor(v, 2);
      v += __shfl_xor(v, 4);
      v += __shfl_xor(v, 8);
      if (l16 == 0) atomicAdd(&rsumS[rbase + pi * 16 + quad * 4 + r], v);
    }
  // col sums (mirror band): reduce across quads, stage in LDS
#pragma unroll
  for (int pj = 0; pj < 4; ++pj) {
    float v = colp[pj];
    v += __shfl_xor(v, 16);
    v += __shfl_xor(v, 32);
    if (quad == 0) atomicAdd(&csumS[cbase + pj * 16 + l16], v);
  }
  __syncthreads();

  // flush: PLAIN coalesced stores to per-block partial slots (no atomics)
  if (t < 128) {
    rpart[(size_t)b * 128 + t] = rsumS[t];
  } else if (offdiag) {
    cpart[(size_t)b * 128 + (t - 128)] = csumS[t - 128];
  }
  // flush positive records: one global cursor atomic per block
  int total = posCnt < PCAP ? posCnt : PCAP;
  if (t == 0) gbaseS = atomicAdd(pcur, total);
  __syncthreads();
  for (int e = t; e < total; e += 256) posBuf[gbaseS + e] = posS[e];
}

// ---------------------------------------------------------------------------
// Kernel 3: reduce per-block partials into unsim. One block per 128-row
// band k: unsim[k][r] = sum_{bj>=k} rpart[b(k,bj)][r]
//                     + sum_{bi<k}  cpart[b(bi,k)][r].
// Lanes vary r -> every gather iteration is a coalesced 512B read.
__global__ __launch_bounds__(256) void reduce_kernel(
    const float* __restrict__ rpart, const float* __restrict__ cpart,
    float* __restrict__ unsim, int nt) {
  __shared__ float part[2][128];
  int k = blockIdx.x;
  int t = threadIdx.x;
  int r = t & 127, h = t >> 7;  // 2-way split of the gather loop
  float s = 0.f;
  int basek = k * nt - (k * (k - 1)) / 2;
  for (int bj = k + h; bj < nt; bj += 2)
    s += rpart[(size_t)(basek + (bj - k)) * 128 + r];
  for (int bi = h; bi < k; bi += 2)
    s += cpart[(size_t)(bi * nt - (bi * (bi - 1)) / 2 + (k - bi)) * 128 + r];
  part[h][r] = s;
  __syncthreads();
  if (t < 128) unsim[k * 128 + t] = part[0][t] + part[1][t];
}

// ---------------------------------------------------------------------------
// Kernel 4: stream positive records: term = log(exp(s) + unsim[idx]) - s,
// finalize fused via last-block-done pattern.
__global__ __launch_bounds__(256) void pass3_kernel(
    const uint2* __restrict__ posBuf, int* __restrict__ pcur,
    const float* __restrict__ unsim, float* __restrict__ accum,
    float* __restrict__ out) {
  int n = *pcur;
  float local = 0.f;
  int stride = 256 * gridDim.x;
  for (int p = blockIdx.x * 256 + threadIdx.x; p < n; p += stride) {
    uint2 e = posBuf[p];
    float s = __uint_as_float(e.y);
    local += __logf(__expf(s) + unsim[e.x]) - s;
  }
  __shared__ float red[4];
#pragma unroll
  for (int msk = 1; msk < 64; msk <<= 1) local += __shfl_xor(local, msk);
  int lane = threadIdx.x & 63, w = threadIdx.x >> 6;
  if (lane == 0) red[w] = local;
  __syncthreads();
  if (threadIdx.x == 0) {
    atomicAdd(&accum[0], red[0] + red[1] + red[2] + red[3]);
    __threadfence();
    int* done = (int*)&accum[2];
    if (atomicAdd(done, 1) == (int)gridDim.x - 1) {
      float ls = __hip_atomic_load(&accum[0], __ATOMIC_ACQUIRE,
                                   __HIP_MEMORY_SCOPE_AGENT);
      out[0] = ls / (float)n;
    }
  }
}

// ---------------------------------------------------------------------------
extern "C" void kernel_launch(void* const* d_in, const int* in_sizes, int n_in,
                              void* d_out, int out_size, void* d_ws,
                              size_t ws_size, hipStream_t stream) {
  const float* X = (const float*)d_in[0];
  const int* lab = (const int*)d_in[1];
  float* out = (float*)d_out;

  const int N = in_sizes[1];           // 8192; D fixed at 128
  const int nt = N / 128;              // 64 tiles per dim
  const int nblk = nt * (nt + 1) / 2;  // 2080 upper-tri tile pairs

  // workspace layout
  unsigned char* Y8 = (unsigned char*)d_ws;       // N*128 fp8 (1 MB)
  float* unsim = (float*)(Y8 + (size_t)N * 128);  // N f32
  float* accum = unsim + N;                       // [0] loss, [2] done ctr
  int* pcur = (int*)(accum + 6);                  // record cursor (+ pad)
  float* rpart = (float*)(pcur + 2);              // nblk*128 f32 (1.07 MB)
  float* cpart = rpart + (size_t)nblk * 128;      // nblk*128 f32 (1.07 MB)
  uint2* posBuf = (uint2*)(cpart + (size_t)nblk * 128);  // ~524k entries

  const float inv_sqrtT = 2.2360679775f;  // 1/sqrt(0.2)
  norm_kernel<<<N / 4, 256, 0, stream>>>(X, Y8, accum, inv_sqrtT);
  pass1_kernel<<<nblk, 256, 0, stream>>>(Y8, lab, rpart, cpart, posBuf, pcur,
                                         nt);
  reduce_kernel<<<nt, 256, 0, stream>>>(rpart, cpart, unsim, nt);
  pass3_kernel<<<512, 256, 0, stream>>>(posBuf, pcur, unsim, accum, out);
}

// Round 12
// 124.508 us; speedup vs baseline: 2.2237x; 1.1668x over previous
//
#include <hip/hip_runtime.h>
#include <math.h>

#define PCAP 512  // per-block LDS positive-pair staging capacity

typedef float f32x4 __attribute__((ext_vector_type(4)));
typedef __attribute__((address_space(3))) unsigned int lds_u32;
typedef __attribute__((address_space(1))) const unsigned int glb_u32;

// ---------------------------------------------------------------------------
// Kernel 1: row normalization (4 rows per block, one per wave) + zero
// unsim/accum/pcur. Output: fp8 e4m3 rows in a PRE-SWIZZLED layout:
// 16B chunk c of row r is stored at chunk (c ^ (r&7)). pass1 then stages
// rows verbatim with async global_load_lds and reads with the same swizzle.
__global__ __launch_bounds__(256) void norm_kernel(
    const float* __restrict__ X, unsigned char* __restrict__ Y8,
    float* __restrict__ unsim, float* __restrict__ accum, float inv_sqrtT) {
  int t = threadIdx.x;
  int w = t >> 6, lane = t & 63;
  int row = blockIdx.x * 4 + w;
  float2 v = ((const float2*)(X + (size_t)row * 128))[lane];
  float s = v.x * v.x + v.y * v.y;
#pragma unroll
  for (int m = 1; m < 64; m <<= 1) s += __shfl_xor(s, m);
  float inv = inv_sqrtT * rsqrtf(fmaxf(s, 1e-24f));
  int packed = __builtin_amdgcn_cvt_pk_fp8_f32(v.x * inv, v.y * inv, 0, false);
  // swizzled byte offset for this lane's 2 bytes (byte = lane*2)
  int chunk = lane >> 3;
  int off = ((chunk ^ (row & 7)) << 4) + ((lane & 7) << 1);
  *(unsigned short*)(Y8 + (size_t)row * 128 + off) =
      (unsigned short)(packed & 0xffff);
  if (t < 4) unsim[blockIdx.x * 4 + t] = 0.f;
  if (blockIdx.x == 0 && t < 8) accum[t] = 0.f;  // accum[0..5] + pcur(6,7)
}

// ---------------------------------------------------------------------------
// Kernel 2: fp8 MFMA similarity pass over upper-triangular 128x128 tile
// pairs (R7 structure). Staging now uses async global_load_lds width=16:
// per-lane contiguous 1KB global segments -> wave-uniform LDS base + lane*16
// (swizzle pre-baked in Y8), removing the load->VGPR->ds_write round trip
// from the pre-barrier critical path. Epilogue unchanged from R7.
__global__ __launch_bounds__(256, 4) void pass1_kernel(
    const unsigned char* __restrict__ Y8, const int* __restrict__ lab,
    float* __restrict__ unsim, uint2* __restrict__ posBuf,
    int* __restrict__ pcur, int nt) {
  __shared__ unsigned char As[128][128];  // chunk c at (c ^ (row&7)) * 16
  __shared__ unsigned char Bs[128][128];
  __shared__ int labR[128], labC[128];
  __shared__ float rsumS[128], csumS[128];
  __shared__ uint2 posS[PCAP];
  __shared__ int posCnt, gbaseS;

  // decode linear block id -> (bi, bj), bi <= bj (triangular)
  int b = blockIdx.x;
  float ntf = (float)nt;
  int bi = (int)((2.f * ntf + 1.f -
                  sqrtf((2.f * ntf + 1.f) * (2.f * ntf + 1.f) - 8.f * (float)b)) *
                 0.5f);
  if (bi < 0) bi = 0;
  while ((bi + 1) * nt - ((bi + 1) * bi) / 2 <= b) ++bi;
  while (bi * nt - (bi * (bi - 1)) / 2 > b) --bi;
  int bj = bi + (b - (bi * nt - (bi * (bi - 1)) / 2));
  const int i0 = bi * 128, j0 = bj * 128;
  const bool offdiag = (bi != bj);

  const int t = threadIdx.x;
  const int w = t >> 6, lane = t & 63;

  // ---- async staging: 4 x (A,B) 1KB segments per wave ----
#pragma unroll
  for (int k = 0; k < 4; ++k) {
    const int c0 = w * 64 + k * 256;  // wave-uniform 16B-chunk index
    const int c = c0 + lane;
    __builtin_amdgcn_global_load_lds(
        (glb_u32*)(Y8 + (size_t)i0 * 128 + (size_t)c * 16),
        (lds_u32*)((unsigned char*)&As[0][0] + c0 * 16), 16, 0, 0);
    __builtin_amdgcn_global_load_lds(
        (glb_u32*)(Y8 + (size_t)j0 * 128 + (size_t)c * 16),
        (lds_u32*)((unsigned char*)&Bs[0][0] + c0 * 16), 16, 0, 0);
  }
  if (t < 128) {
    labR[t] = lab[i0 + t];
    labC[t] = lab[j0 + t];
    rsumS[t] = 0.f;
    csumS[t] = 0.f;
  }
  if (t == 0) posCnt = 0;
  __syncthreads();  // drains vmcnt (global_load_lds) + lgkmcnt

  const int quad = lane >> 4, l16 = lane & 15;
  const int rbase = (w >> 1) * 64, cbase = (w & 1) * 64;
  const int sw = l16 & 7;

  f32x4 acc[4][4] = {};
#pragma unroll
  for (int ks = 0; ks < 4; ++ks) {
    const int ch = ks * 2 + (quad >> 1);
    const int off = ((ch ^ sw) << 4) + ((quad & 1) << 3);
    long af[4], bf[4];
#pragma unroll
    for (int p = 0; p < 4; ++p)
      af[p] = *(const long*)&As[rbase + p * 16 + l16][off];
#pragma unroll
    for (int p = 0; p < 4; ++p)
      bf[p] = *(const long*)&Bs[cbase + p * 16 + l16][off];
#pragma unroll
    for (int pi = 0; pi < 4; ++pi)
#pragma unroll
      for (int pj = 0; pj < 4; ++pj)
        acc[pi][pj] = __builtin_amdgcn_mfma_f32_16x16x32_fp8_fp8(
            af[pi], bf[pj], acc[pi][pj], 0, 0, 0);
  }

  // ---- epilogue ----
  int lr[4][4], lc[4];
#pragma unroll
  for (int pi = 0; pi < 4; ++pi)
#pragma unroll
    for (int r = 0; r < 4; ++r) lr[pi][r] = labR[rbase + pi * 16 + quad * 4 + r];
#pragma unroll
  for (int pj = 0; pj < 4; ++pj) lc[pj] = labC[cbase + pj * 16 + l16];

  float rowp[4][4] = {};
  float colp[4] = {0.f, 0.f, 0.f, 0.f};
#pragma unroll
  for (int pi = 0; pi < 4; ++pi)
#pragma unroll
    for (int pj = 0; pj < 4; ++pj)
#pragma unroll
      for (int r = 0; r < 4; ++r) {
        const bool same = (lr[pi][r] == lc[pj]);
        float s = acc[pi][pj][r];
        float e = same ? 0.f : __expf(s);
        rowp[pi][r] += e;
        colp[pj] += e;
        if (same) {  // rare (~1/128): LDS-staged append
          const int gi = i0 + rbase + pi * 16 + quad * 4 + r;
          const int gj = j0 + cbase + pj * 16 + l16;
          if (offdiag || (gi != gj)) {
            int nadd = offdiag ? 2 : 1;
            int s0 = atomicAdd(&posCnt, nadd);
            unsigned sb = __float_as_uint(s);
            uint2 e0 = {(unsigned)gi, sb};
            if (s0 < PCAP) posS[s0] = e0;
            else posBuf[atomicAdd(pcur, 1)] = e0;
            if (offdiag) {
              uint2 e1 = {(unsigned)gj, sb};
              if (s0 + 1 < PCAP) posS[s0 + 1] = e1;
              else posBuf[atomicAdd(pcur, 1)] = e1;
            }
          }
        }
      }

  // row sums: 4-shfl reduce over the 16 cols, stage in LDS
#pragma unroll
  for (int pi = 0; pi < 4; ++pi)
#pragma unroll
    for (int r = 0; r < 4; ++r) {
      float v = rowp[pi][r];
      v += __shfl_xor(v, 1);
      v += __shfl_xor(v, 2);
      v += __shfl_xor(v, 4);
      v += __shfl_xor(v, 8);
      if (l16 == 0) atomicAdd(&rsumS[rbase + pi * 16 + quad * 4 + r], v);
    }
  // col sums (mirror band): reduce across quads, stage in LDS
#pragma unroll
  for (int pj = 0; pj < 4; ++pj) {
    float v = colp[pj];
    v += __shfl_xor(v, 16);
    v += __shfl_xor(v, 32);
    if (quad == 0) atomicAdd(&csumS[cbase + pj * 16 + l16], v);
  }
  __syncthreads();

  // flush: ONE global atomic per row (and per col if off-diagonal)
  if (t < 128) {
    atomicAdd(&unsim[i0 + t], rsumS[t]);
  } else if (offdiag) {
    atomicAdd(&unsim[j0 + (t - 128)], csumS[t - 128]);
  }
  // flush positive records: one global cursor atomic per block
  int total = posCnt < PCAP ? posCnt : PCAP;
  if (t == 0) gbaseS = atomicAdd(pcur, total);
  __syncthreads();
  for (int e = t; e < total; e += 256) posBuf[gbaseS + e] = posS[e];
}

// ---------------------------------------------------------------------------
// Kernel 3: stream positive records: term = log(exp(s) + unsim[idx]) - s,
// finalize fused via last-block-done pattern.
__global__ __launch_bounds__(256) void pass3_kernel(
    const uint2* __restrict__ posBuf, int* __restrict__ pcur,
    const float* __restrict__ unsim, float* __restrict__ accum,
    float* __restrict__ out) {
  int n = *pcur;
  float local = 0.f;
  int stride = 256 * gridDim.x;
  for (int p = blockIdx.x * 256 + threadIdx.x; p < n; p += stride) {
    uint2 e = posBuf[p];
    float s = __uint_as_float(e.y);
    local += __logf(__expf(s) + unsim[e.x]) - s;
  }
  __shared__ float red[4];
#pragma unroll
  for (int msk = 1; msk < 64; msk <<= 1) local += __shfl_xor(local, msk);
  int lane = threadIdx.x & 63, w = threadIdx.x >> 6;
  if (lane == 0) red[w] = local;
  __syncthreads();
  if (threadIdx.x == 0) {
    atomicAdd(&accum[0], red[0] + red[1] + red[2] + red[3]);
    __threadfence();
    int* done = (int*)&accum[2];
    if (atomicAdd(done, 1) == (int)gridDim.x - 1) {
      float ls = __hip_atomic_load(&accum[0], __ATOMIC_ACQUIRE,
                                   __HIP_MEMORY_SCOPE_AGENT);
      out[0] = ls / (float)n;
    }
  }
}

// ---------------------------------------------------------------------------
extern "C" void kernel_launch(void* const* d_in, const int* in_sizes, int n_in,
                              void* d_out, int out_size, void* d_ws,
                              size_t ws_size, hipStream_t stream) {
  const float* X = (const float*)d_in[0];
  const int* lab = (const int*)d_in[1];
  float* out = (float*)d_out;

  const int N = in_sizes[1];  // 8192; D fixed at 128

  // workspace layout
  unsigned char* Y8 = (unsigned char*)d_ws;       // N*128 fp8 (1 MB)
  float* unsim = (float*)(Y8 + (size_t)N * 128);  // N f32
  float* accum = unsim + N;                       // [0] loss, [2] done ctr
  int* pcur = (int*)(accum + 6);                  // record cursor (+ pad)
  uint2* posBuf = (uint2*)(pcur + 2);             // ~524k entries (4.2 MB)

  const float inv_sqrtT = 2.2360679775f;  // 1/sqrt(0.2)
  norm_kernel<<<N / 4, 256, 0, stream>>>(X, Y8, unsim, accum, inv_sqrtT);

  const int nt = N / 128;              // 64 tiles per dim
  const int nblk = nt * (nt + 1) / 2;  // 2080 upper-tri tile pairs
  pass1_kernel<<<nblk, 256, 0, stream>>>(Y8, lab, unsim, posBuf, pcur, nt);
  pass3_kernel<<<512, 256, 0, stream>>>(posBuf, pcur, unsim, accum, out);
}

// Round 13
// 120.939 us; speedup vs baseline: 2.2893x; 1.0295x over previous
//
#include <hip/hip_runtime.h>
#include <math.h>

#define PCAP 512  // per-block LDS positive-pair staging capacity (u32 records)

typedef float f32x4 __attribute__((ext_vector_type(4)));
typedef __attribute__((address_space(3))) unsigned int lds_u32;
typedef __attribute__((address_space(1))) const unsigned int glb_u32;

// ---------------------------------------------------------------------------
// Kernel 1: row normalization (4 rows per block, one per wave) + zero
// unsim/accum/pcur. Output: fp8 e4m3 rows in a PRE-SWIZZLED layout:
// 16B chunk c of row r is stored at chunk (c ^ (r&7)). pass1 then stages
// rows verbatim with async global_load_lds and reads with the same swizzle.
__global__ __launch_bounds__(256) void norm_kernel(
    const float* __restrict__ X, unsigned char* __restrict__ Y8,
    float* __restrict__ unsim, float* __restrict__ accum, float inv_sqrtT) {
  int t = threadIdx.x;
  int w = t >> 6, lane = t & 63;
  int row = blockIdx.x * 4 + w;
  float2 v = ((const float2*)(X + (size_t)row * 128))[lane];
  float s = v.x * v.x + v.y * v.y;
#pragma unroll
  for (int m = 1; m < 64; m <<= 1) s += __shfl_xor(s, m);
  float inv = inv_sqrtT * rsqrtf(fmaxf(s, 1e-24f));
  int packed = __builtin_amdgcn_cvt_pk_fp8_f32(v.x * inv, v.y * inv, 0, false);
  // swizzled byte offset for this lane's 2 bytes (byte = lane*2)
  int chunk = lane >> 3;
  int off = ((chunk ^ (row & 7)) << 4) + ((lane & 7) << 1);
  *(unsigned short*)(Y8 + (size_t)row * 128 + off) =
      (unsigned short)(packed & 0xffff);
  if (t < 4) unsim[blockIdx.x * 4 + t] = 0.f;
  if (blockIdx.x == 0 && t < 8) accum[t] = 0.f;  // accum[0..5] + pcur(6,7)
}

// ---------------------------------------------------------------------------
// Kernel 2: fp8 MFMA similarity pass over upper-triangular 128x128 tile
// pairs (R12 structure: async global_load_lds staging, pre-swizzled Y8).
// Positive records now packed to u32: (gi<<16) | fp16(s)  — halves posS LDS
// (total ~36.9 KB -> 4 blocks/CU target) and halves posBuf traffic.
// fp16(s) abs err <=0.004 on s in [-5,5]; loss term ~= log(unsim)-s, so the
// induced error is ~0.004 << the 0.18 threshold.
__global__ __launch_bounds__(256, 4) void pass1_kernel(
    const unsigned char* __restrict__ Y8, const int* __restrict__ lab,
    float* __restrict__ unsim, unsigned* __restrict__ posBuf,
    int* __restrict__ pcur, int nt) {
  __shared__ unsigned char As[128][128];  // chunk c at (c ^ (row&7)) * 16
  __shared__ unsigned char Bs[128][128];
  __shared__ int labR[128], labC[128];
  __shared__ float rsumS[128], csumS[128];
  __shared__ unsigned posS[PCAP];
  __shared__ int posCnt, gbaseS;

  // decode linear block id -> (bi, bj), bi <= bj (triangular)
  int b = blockIdx.x;
  float ntf = (float)nt;
  int bi = (int)((2.f * ntf + 1.f -
                  sqrtf((2.f * ntf + 1.f) * (2.f * ntf + 1.f) - 8.f * (float)b)) *
                 0.5f);
  if (bi < 0) bi = 0;
  while ((bi + 1) * nt - ((bi + 1) * bi) / 2 <= b) ++bi;
  while (bi * nt - (bi * (bi - 1)) / 2 > b) --bi;
  int bj = bi + (b - (bi * nt - (bi * (bi - 1)) / 2));
  const int i0 = bi * 128, j0 = bj * 128;
  const bool offdiag = (bi != bj);

  const int t = threadIdx.x;
  const int w = t >> 6, lane = t & 63;

  // ---- async staging: 4 x (A,B) 1KB segments per wave ----
#pragma unroll
  for (int k = 0; k < 4; ++k) {
    const int c0 = w * 64 + k * 256;  // wave-uniform 16B-chunk index
    const int c = c0 + lane;
    __builtin_amdgcn_global_load_lds(
        (glb_u32*)(Y8 + (size_t)i0 * 128 + (size_t)c * 16),
        (lds_u32*)((unsigned char*)&As[0][0] + c0 * 16), 16, 0, 0);
    __builtin_amdgcn_global_load_lds(
        (glb_u32*)(Y8 + (size_t)j0 * 128 + (size_t)c * 16),
        (lds_u32*)((unsigned char*)&Bs[0][0] + c0 * 16), 16, 0, 0);
  }
  if (t < 128) {
    labR[t] = lab[i0 + t];
    labC[t] = lab[j0 + t];
    rsumS[t] = 0.f;
    csumS[t] = 0.f;
  }
  if (t == 0) posCnt = 0;
  __syncthreads();  // drains vmcnt (global_load_lds) + lgkmcnt

  const int quad = lane >> 4, l16 = lane & 15;
  const int rbase = (w >> 1) * 64, cbase = (w & 1) * 64;
  const int sw = l16 & 7;

  f32x4 acc[4][4] = {};
#pragma unroll
  for (int ks = 0; ks < 4; ++ks) {
    const int ch = ks * 2 + (quad >> 1);
    const int off = ((ch ^ sw) << 4) + ((quad & 1) << 3);
    long af[4], bf[4];
#pragma unroll
    for (int p = 0; p < 4; ++p)
      af[p] = *(const long*)&As[rbase + p * 16 + l16][off];
#pragma unroll
    for (int p = 0; p < 4; ++p)
      bf[p] = *(const long*)&Bs[cbase + p * 16 + l16][off];
#pragma unroll
    for (int pi = 0; pi < 4; ++pi)
#pragma unroll
      for (int pj = 0; pj < 4; ++pj)
        acc[pi][pj] = __builtin_amdgcn_mfma_f32_16x16x32_fp8_fp8(
            af[pi], bf[pj], acc[pi][pj], 0, 0, 0);
  }

  // ---- epilogue ----
  int lr[4][4], lc[4];
#pragma unroll
  for (int pi = 0; pi < 4; ++pi)
#pragma unroll
    for (int r = 0; r < 4; ++r) lr[pi][r] = labR[rbase + pi * 16 + quad * 4 + r];
#pragma unroll
  for (int pj = 0; pj < 4; ++pj) lc[pj] = labC[cbase + pj * 16 + l16];

  float rowp[4][4] = {};
  float colp[4] = {0.f, 0.f, 0.f, 0.f};
#pragma unroll
  for (int pi = 0; pi < 4; ++pi)
#pragma unroll
    for (int pj = 0; pj < 4; ++pj)
#pragma unroll
      for (int r = 0; r < 4; ++r) {
        const bool same = (lr[pi][r] == lc[pj]);
        float s = acc[pi][pj][r];
        float e = same ? 0.f : __expf(s);
        rowp[pi][r] += e;
        colp[pj] += e;
        if (same) {  // rare (~1/128): LDS-staged packed append
          const int gi = i0 + rbase + pi * 16 + quad * 4 + r;
          const int gj = j0 + cbase + pj * 16 + l16;
          if (offdiag || (gi != gj)) {
            int nadd = offdiag ? 2 : 1;
            int s0 = atomicAdd(&posCnt, nadd);
            _Float16 hs = (_Float16)s;
            unsigned hb = (unsigned)__builtin_bit_cast(unsigned short, hs);
            unsigned e0 = ((unsigned)gi << 16) | hb;
            if (s0 < PCAP) posS[s0] = e0;
            else posBuf[atomicAdd(pcur, 1)] = e0;
            if (offdiag) {
              unsigned e1 = ((unsigned)gj << 16) | hb;
              if (s0 + 1 < PCAP) posS[s0 + 1] = e1;
              else posBuf[atomicAdd(pcur, 1)] = e1;
            }
          }
        }
      }

  // row sums: 4-shfl reduce over the 16 cols, stage in LDS
#pragma unroll
  for (int pi = 0; pi < 4; ++pi)
#pragma unroll
    for (int r = 0; r < 4; ++r) {
      float v = rowp[pi][r];
      v += __shfl_xor(v, 1);
      v += __shfl_xor(v, 2);
      v += __shfl_xor(v, 4);
      v += __shfl_xor(v, 8);
      if (l16 == 0) atomicAdd(&rsumS[rbase + pi * 16 + quad * 4 + r], v);
    }
  // col sums (mirror band): reduce across quads, stage in LDS
#pragma unroll
  for (int pj = 0; pj < 4; ++pj) {
    float v = colp[pj];
    v += __shfl_xor(v, 16);
    v += __shfl_xor(v, 32);
    if (quad == 0) atomicAdd(&csumS[cbase + pj * 16 + l16], v);
  }
  __syncthreads();

  // flush: ONE global atomic per row (and per col if off-diagonal)
  if (t < 128) {
    atomicAdd(&unsim[i0 + t], rsumS[t]);
  } else if (offdiag) {
    atomicAdd(&unsim[j0 + (t - 128)], csumS[t - 128]);
  }
  // flush positive records: one global cursor atomic per block
  int total = posCnt < PCAP ? posCnt : PCAP;
  if (t == 0) gbaseS = atomicAdd(pcur, total);
  __syncthreads();
  for (int e = t; e < total; e += 256) posBuf[gbaseS + e] = posS[e];
}

// ---------------------------------------------------------------------------
// Kernel 3: stream packed positive records: rec = (idx<<16)|fp16(s);
// term = log(exp(s) + unsim[idx]) - s. Finalize fused via last-block-done.
__global__ __launch_bounds__(256) void pass3_kernel(
    const unsigned* __restrict__ posBuf, int* __restrict__ pcur,
    const float* __restrict__ unsim, float* __restrict__ accum,
    float* __restrict__ out) {
  int n = *pcur;
  float local = 0.f;
  int stride = 256 * gridDim.x;
  for (int p = blockIdx.x * 256 + threadIdx.x; p < n; p += stride) {
    unsigned rec = posBuf[p];
    unsigned short hb = (unsigned short)(rec & 0xffffu);
    float s = (float)__builtin_bit_cast(_Float16, hb);
    local += __logf(__expf(s) + unsim[rec >> 16]) - s;
  }
  __shared__ float red[4];
#pragma unroll
  for (int msk = 1; msk < 64; msk <<= 1) local += __shfl_xor(local, msk);
  int lane = threadIdx.x & 63, w = threadIdx.x >> 6;
  if (lane == 0) red[w] = local;
  __syncthreads();
  if (threadIdx.x == 0) {
    atomicAdd(&accum[0], red[0] + red[1] + red[2] + red[3]);
    __threadfence();
    int* done = (int*)&accum[2];
    if (atomicAdd(done, 1) == (int)gridDim.x - 1) {
      float ls = __hip_atomic_load(&accum[0], __ATOMIC_ACQUIRE,
                                   __HIP_MEMORY_SCOPE_AGENT);
      out[0] = ls / (float)n;
    }
  }
}

// ---------------------------------------------------------------------------
extern "C" void kernel_launch(void* const* d_in, const int* in_sizes, int n_in,
                              void* d_out, int out_size, void* d_ws,
                              size_t ws_size, hipStream_t stream) {
  const float* X = (const float*)d_in[0];
  const int* lab = (const int*)d_in[1];
  float* out = (float*)d_out;

  const int N = in_sizes[1];  // 8192; D fixed at 128

  // workspace layout
  unsigned char* Y8 = (unsigned char*)d_ws;       // N*128 fp8 (1 MB)
  float* unsim = (float*)(Y8 + (size_t)N * 128);  // N f32
  float* accum = unsim + N;                       // [0] loss, [2] done ctr
  int* pcur = (int*)(accum + 6);                  // record cursor (+ pad)
  unsigned* posBuf = (unsigned*)(pcur + 2);       // ~524k u32 (2.1 MB)

  const float inv_sqrtT = 2.2360679775f;  // 1/sqrt(0.2)
  norm_kernel<<<N / 4, 256, 0, stream>>>(X, Y8, unsim, accum, inv_sqrtT);

  const int nt = N / 128;              // 64 tiles per dim
  const int nblk = nt * (nt + 1) / 2;  // 2080 upper-tri tile pairs
  pass1_kernel<<<nblk, 256, 0, stream>>>(Y8, lab, unsim, posBuf, pcur, nt);
  pass3_kernel<<<512, 256, 0, stream>>>(posBuf, pcur, unsim, accum, out);
}

// Round 14
// 117.788 us; speedup vs baseline: 2.3505x; 1.0268x over previous
//
#include <hip/hip_runtime.h>
#include <math.h>

#define PCAP 512  // per-block LDS positive-pair staging capacity (u32 records)

typedef float f32x4 __attribute__((ext_vector_type(4)));
typedef __attribute__((address_space(3))) unsigned int lds_u32;
typedef __attribute__((address_space(1))) const unsigned int glb_u32;

// ---------------------------------------------------------------------------
// Kernel 1: row normalization (4 rows per block, one per wave) + zero
// unsim/accum/pcur. Output: fp8 e4m3 rows in a PRE-SWIZZLED layout:
// 16B chunk c of row r is stored at chunk (c ^ (r&7)). pass1 then stages
// rows verbatim with async global_load_lds and reads with the same swizzle.
__global__ __launch_bounds__(256) void norm_kernel(
    const float* __restrict__ X, unsigned char* __restrict__ Y8,
    float* __restrict__ unsim, float* __restrict__ accum, float inv_sqrtT) {
  int t = threadIdx.x;
  int w = t >> 6, lane = t & 63;
  int row = blockIdx.x * 4 + w;
  float2 v = ((const float2*)(X + (size_t)row * 128))[lane];
  float s = v.x * v.x + v.y * v.y;
#pragma unroll
  for (int m = 1; m < 64; m <<= 1) s += __shfl_xor(s, m);
  float inv = inv_sqrtT * rsqrtf(fmaxf(s, 1e-24f));
  int packed = __builtin_amdgcn_cvt_pk_fp8_f32(v.x * inv, v.y * inv, 0, false);
  // swizzled byte offset for this lane's 2 bytes (byte = lane*2)
  int chunk = lane >> 3;
  int off = ((chunk ^ (row & 7)) << 4) + ((lane & 7) << 1);
  *(unsigned short*)(Y8 + (size_t)row * 128 + off) =
      (unsigned short)(packed & 0xffff);
  if (t < 4) unsim[blockIdx.x * 4 + t] = 0.f;
  if (blockIdx.x == 0 && t < 8) accum[t] = 0.f;  // accum[0..5] + pcur(6,7)
}

// ---------------------------------------------------------------------------
// Kernel 2: fp8 MFMA similarity pass over upper-triangular 128x128 tile
// pairs. NEW: 512-thread blocks, 8 waves each owning a 32x64 quadrant —
// halves per-wave acc registers (32 vs 64) and per-wave issue work, so
// 3 resident blocks give 6 waves/SIMD (vs 3 with 256-thr blocks): 2x
// latency hiding at identical LDS footprint. Staging via async
// global_load_lds (pre-swizzled Y8). Packed u32 positive records.
__global__ __launch_bounds__(512, 6) void pass1_kernel(
    const unsigned char* __restrict__ Y8, const int* __restrict__ lab,
    float* __restrict__ unsim, unsigned* __restrict__ posBuf,
    int* __restrict__ pcur, int nt) {
  __shared__ unsigned char As[128][128];  // chunk c at (c ^ (row&7)) * 16
  __shared__ unsigned char Bs[128][128];
  __shared__ int labR[128], labC[128];
  __shared__ float rsumS[128], csumS[128];
  __shared__ unsigned posS[PCAP];
  __shared__ int posCnt, gbaseS;

  // decode linear block id -> (bi, bj), bi <= bj (triangular)
  int b = blockIdx.x;
  float ntf = (float)nt;
  int bi = (int)((2.f * ntf + 1.f -
                  sqrtf((2.f * ntf + 1.f) * (2.f * ntf + 1.f) - 8.f * (float)b)) *
                 0.5f);
  if (bi < 0) bi = 0;
  while ((bi + 1) * nt - ((bi + 1) * bi) / 2 <= b) ++bi;
  while (bi * nt - (bi * (bi - 1)) / 2 > b) --bi;
  int bj = bi + (b - (bi * nt - (bi * (bi - 1)) / 2));
  const int i0 = bi * 128, j0 = bj * 128;
  const bool offdiag = (bi != bj);

  const int t = threadIdx.x;
  const int w = t >> 6, lane = t & 63;

  // ---- async staging: 2 x (A,B) 1KB segments per wave (8 waves) ----
#pragma unroll
  for (int k = 0; k < 2; ++k) {
    const int c0 = w * 64 + k * 512;  // wave-uniform 16B-chunk index
    const int c = c0 + lane;
    __builtin_amdgcn_global_load_lds(
        (glb_u32*)(Y8 + (size_t)i0 * 128 + (size_t)c * 16),
        (lds_u32*)((unsigned char*)&As[0][0] + c0 * 16), 16, 0, 0);
    __builtin_amdgcn_global_load_lds(
        (glb_u32*)(Y8 + (size_t)j0 * 128 + (size_t)c * 16),
        (lds_u32*)((unsigned char*)&Bs[0][0] + c0 * 16), 16, 0, 0);
  }
  if (t < 128) {
    labR[t] = lab[i0 + t];
    rsumS[t] = 0.f;
  } else if (t < 256) {
    labC[t - 128] = lab[j0 + t - 128];
    csumS[t - 128] = 0.f;
  }
  if (t == 0) posCnt = 0;
  __syncthreads();  // drains vmcnt (global_load_lds) + lgkmcnt

  const int quad = lane >> 4, l16 = lane & 15;
  const int rbase = (w >> 1) * 32, cbase = (w & 1) * 64;  // 32x64 quadrant
  const int sw = l16 & 7;

  f32x4 acc[2][4] = {};
#pragma unroll
  for (int ks = 0; ks < 4; ++ks) {
    const int ch = ks * 2 + (quad >> 1);
    const int off = ((ch ^ sw) << 4) + ((quad & 1) << 3);
    long af[2], bf[4];
#pragma unroll
    for (int p = 0; p < 2; ++p)
      af[p] = *(const long*)&As[rbase + p * 16 + l16][off];
#pragma unroll
    for (int p = 0; p < 4; ++p)
      bf[p] = *(const long*)&Bs[cbase + p * 16 + l16][off];
#pragma unroll
    for (int pi = 0; pi < 2; ++pi)
#pragma unroll
      for (int pj = 0; pj < 4; ++pj)
        acc[pi][pj] = __builtin_amdgcn_mfma_f32_16x16x32_fp8_fp8(
            af[pi], bf[pj], acc[pi][pj], 0, 0, 0);
  }

  // ---- epilogue ----
  int lr[2][4], lc[4];
#pragma unroll
  for (int pi = 0; pi < 2; ++pi)
#pragma unroll
    for (int r = 0; r < 4; ++r) lr[pi][r] = labR[rbase + pi * 16 + quad * 4 + r];
#pragma unroll
  for (int pj = 0; pj < 4; ++pj) lc[pj] = labC[cbase + pj * 16 + l16];

  float rowp[2][4] = {};
  float colp[4] = {0.f, 0.f, 0.f, 0.f};
#pragma unroll
  for (int pi = 0; pi < 2; ++pi)
#pragma unroll
    for (int pj = 0; pj < 4; ++pj)
#pragma unroll
      for (int r = 0; r < 4; ++r) {
        const bool same = (lr[pi][r] == lc[pj]);
        float s = acc[pi][pj][r];
        float e = same ? 0.f : __expf(s);
        rowp[pi][r] += e;
        colp[pj] += e;
        if (same) {  // rare (~1/128): LDS-staged packed append
          const int gi = i0 + rbase + pi * 16 + quad * 4 + r;
          const int gj = j0 + cbase + pj * 16 + l16;
          if (offdiag || (gi != gj)) {
            int nadd = offdiag ? 2 : 1;
            int s0 = atomicAdd(&posCnt, nadd);
            _Float16 hs = (_Float16)s;
            unsigned hb = (unsigned)__builtin_bit_cast(unsigned short, hs);
            unsigned e0 = ((unsigned)gi << 16) | hb;
            if (s0 < PCAP) posS[s0] = e0;
            else posBuf[atomicAdd(pcur, 1)] = e0;
            if (offdiag) {
              unsigned e1 = ((unsigned)gj << 16) | hb;
              if (s0 + 1 < PCAP) posS[s0 + 1] = e1;
              else posBuf[atomicAdd(pcur, 1)] = e1;
            }
          }
        }
      }

  // row sums: 4-shfl reduce over the 16 cols, stage in LDS
#pragma unroll
  for (int pi = 0; pi < 2; ++pi)
#pragma unroll
    for (int r = 0; r < 4; ++r) {
      float v = rowp[pi][r];
      v += __shfl_xor(v, 1);
      v += __shfl_xor(v, 2);
      v += __shfl_xor(v, 4);
      v += __shfl_xor(v, 8);
      if (l16 == 0) atomicAdd(&rsumS[rbase + pi * 16 + quad * 4 + r], v);
    }
  // col sums (mirror band): reduce across quads (32 rows), stage in LDS
#pragma unroll
  for (int pj = 0; pj < 4; ++pj) {
    float v = colp[pj];
    v += __shfl_xor(v, 16);
    v += __shfl_xor(v, 32);
    if (quad == 0) atomicAdd(&csumS[cbase + pj * 16 + l16], v);
  }
  __syncthreads();

  // flush: ONE global atomic per row (and per col if off-diagonal)
  if (t < 128) {
    atomicAdd(&unsim[i0 + t], rsumS[t]);
  } else if (t < 256 && offdiag) {
    atomicAdd(&unsim[j0 + (t - 128)], csumS[t - 128]);
  }
  // flush positive records: one global cursor atomic per block
  int total = posCnt < PCAP ? posCnt : PCAP;
  if (t == 0) gbaseS = atomicAdd(pcur, total);
  __syncthreads();
  for (int e = t; e < total; e += 512) posBuf[gbaseS + e] = posS[e];
}

// ---------------------------------------------------------------------------
// Kernel 3: stream packed positive records: rec = (idx<<16)|fp16(s);
// term = log(exp(s) + unsim[idx]) - s. Finalize fused via last-block-done.
__global__ __launch_bounds__(256) void pass3_kernel(
    const unsigned* __restrict__ posBuf, int* __restrict__ pcur,
    const float* __restrict__ unsim, float* __restrict__ accum,
    float* __restrict__ out) {
  int n = *pcur;
  float local = 0.f;
  int stride = 256 * gridDim.x;
  for (int p = blockIdx.x * 256 + threadIdx.x; p < n; p += stride) {
    unsigned rec = posBuf[p];
    unsigned short hb = (unsigned short)(rec & 0xffffu);
    float s = (float)__builtin_bit_cast(_Float16, hb);
    local += __logf(__expf(s) + unsim[rec >> 16]) - s;
  }
  __shared__ float red[4];
#pragma unroll
  for (int msk = 1; msk < 64; msk <<= 1) local += __shfl_xor(local, msk);
  int lane = threadIdx.x & 63, w = threadIdx.x >> 6;
  if (lane == 0) red[w] = local;
  __syncthreads();
  if (threadIdx.x == 0) {
    atomicAdd(&accum[0], red[0] + red[1] + red[2] + red[3]);
    __threadfence();
    int* done = (int*)&accum[2];
    if (atomicAdd(done, 1) == (int)gridDim.x - 1) {
      float ls = __hip_atomic_load(&accum[0], __ATOMIC_ACQUIRE,
                                   __HIP_MEMORY_SCOPE_AGENT);
      out[0] = ls / (float)n;
    }
  }
}

// ---------------------------------------------------------------------------
extern "C" void kernel_launch(void* const* d_in, const int* in_sizes, int n_in,
                              void* d_out, int out_size, void* d_ws,
                              size_t ws_size, hipStream_t stream) {
  const float* X = (const float*)d_in[0];
  const int* lab = (const int*)d_in[1];
  float* out = (float*)d_out;

  const int N = in_sizes[1];  // 8192; D fixed at 128

  // workspace layout
  unsigned char* Y8 = (unsigned char*)d_ws;       // N*128 fp8 (1 MB)
  float* unsim = (float*)(Y8 + (size_t)N * 128);  // N f32
  float* accum = unsim + N;                       // [0] loss, [2] done ctr
  int* pcur = (int*)(accum + 6);                  // record cursor (+ pad)
  unsigned* posBuf = (unsigned*)(pcur + 2);       // ~524k u32 (2.1 MB)

  const float inv_sqrtT = 2.2360679775f;  // 1/sqrt(0.2)
  norm_kernel<<<N / 4, 256, 0, stream>>>(X, Y8, unsim, accum, inv_sqrtT);

  const int nt = N / 128;              // 64 tiles per dim
  const int nblk = nt * (nt + 1) / 2;  // 2080 upper-tri tile pairs
  pass1_kernel<<<nblk, 512, 0, stream>>>(Y8, lab, unsim, posBuf, pcur, nt);
  pass3_kernel<<<512, 256, 0, stream>>>(posBuf, pcur, unsim, accum, out);
}